// Round 11
// baseline (282.294 us; speedup 1.0000x reference)
//
#include <hip/hip_runtime.h>

// LightGCN propagation on MI355X — bf16 states, bucketed CSR, 8-lane SpMM,
// ego-fold + 2-deep gather pipeline.
// R10 lesson: 8-lane + hoisted epilogue = right shape; last still streams
// ego(134 f32)+e1b(67) for the epilogue and has only 2 gathers in flight.
// R11: (1) spmm_first writes s1b = bf16(ego+e1) so last reads 67 instead of
// 201 MB; (2) software-pipeline the edge loop (issue next pair's gathers
// before consuming current) -> 4 outstanding gathers/wave; (3) PB_BLOCKS 256.

constexpr int NUM_USER = 262144;
constexpr int NUM_ITEM = 262144;
constexpr int DIM      = 64;
constexpr int N_NODES  = NUM_USER + NUM_ITEM;   // 524288
constexpr int NNZ      = 1250000;

constexpr int NBUCK = 256;                      // bucket = row >> 11
constexpr int ROWS_PER_BUCK = N_NODES / NBUCK;  // 2048
constexpr int PB_BLOCKS = 256;
constexpr int CHUNK = (NNZ + PB_BLOCKS - 1) / PB_BLOCKS;  // 4883
constexpr int BCAP = 6144;                      // bucket mean 4883, sd ~70

// ---------------- bf16 pack/unpack (RNE) ----------------
__device__ __forceinline__ unsigned bfpack2(float a, float b) {
    unsigned ua = __float_as_uint(a); ua += 0x7fffu + ((ua >> 16) & 1u);
    unsigned ub = __float_as_uint(b); ub += 0x7fffu + ((ub >> 16) & 1u);
    return (ua >> 16) | (ub & 0xffff0000u);
}
__device__ __forceinline__ uint4 bfpack8(float4 a, float4 b) {
    return make_uint4(bfpack2(a.x, a.y), bfpack2(a.z, a.w),
                      bfpack2(b.x, b.y), bfpack2(b.z, b.w));
}
__device__ __forceinline__ void bfunpack8(uint4 u, float4& l, float4& h) {
    l.x = __uint_as_float(u.x << 16);
    l.y = __uint_as_float(u.x & 0xffff0000u);
    l.z = __uint_as_float(u.y << 16);
    l.w = __uint_as_float(u.y & 0xffff0000u);
    h.x = __uint_as_float(u.z << 16);
    h.y = __uint_as_float(u.z & 0xffff0000u);
    h.z = __uint_as_float(u.w << 16);
    h.w = __uint_as_float(u.w & 0xffff0000u);
}
__device__ __forceinline__ void fma4(float4& s, float v, const float4 x) {
    s.x = fmaf(v, x.x, s.x);
    s.y = fmaf(v, x.y, s.y);
    s.z = fmaf(v, x.z, s.z);
    s.w = fmaf(v, x.w, s.w);
}
__device__ __forceinline__ float4 add4(float4 a, float4 b) {
    return make_float4(a.x + b.x, a.y + b.y, a.z + b.z, a.w + b.w);
}

// ---------------- bucket pipeline ----------------
__global__ void bucket_count(const int* __restrict__ rows, int* __restrict__ bcnt) {
    __shared__ int lcnt[NBUCK];
    const int t = threadIdx.x;
    lcnt[t] = 0;
    __syncthreads();
    const int beg = blockIdx.x * CHUNK;
    const int end = min(beg + CHUNK, NNZ);
    for (int i = beg + t; i < end; i += 256)
        atomicAdd(&lcnt[rows[i] >> 11], 1);
    __syncthreads();
    bcnt[t * PB_BLOCKS + blockIdx.x] = lcnt[t];
}

// per bucket, exclusive scan over the 256 block counts (in place)
__global__ void scan_bcnt(int* __restrict__ bcnt, int* __restrict__ tot) {
    __shared__ int tmp[256];
    const int b = blockIdx.x, t = threadIdx.x;
    const int v = bcnt[b * PB_BLOCKS + t];
    tmp[t] = v;
    __syncthreads();
    for (int off = 1; off < 256; off <<= 1) {
        int x = (t >= off) ? tmp[t - off] : 0;
        __syncthreads();
        tmp[t] += x;
        __syncthreads();
    }
    bcnt[b * PB_BLOCKS + t] = tmp[t] - v;
    if (t == 255) tot[b] = tmp[255];
}

__global__ void scan_btot(const int* __restrict__ tot, int* __restrict__ bbase) {
    __shared__ int tmp[256];
    const int t = threadIdx.x;
    const int v = tot[t];
    tmp[t] = v;
    __syncthreads();
    for (int off = 1; off < 256; off <<= 1) {
        int x = (t >= off) ? tmp[t - off] : 0;
        __syncthreads();
        tmp[t] += x;
        __syncthreads();
    }
    bbase[t] = tmp[t] - v;
    if (t == 0) bbase[NBUCK] = NNZ;
}

__global__ void bucket_scatter(const int* __restrict__ rows, const int* __restrict__ cols,
                               const float* __restrict__ vals,
                               const int* __restrict__ bcnt, const int* __restrict__ bbase,
                               int2* __restrict__ eb, unsigned short* __restrict__ ebrow) {
    __shared__ int lbase[NBUCK];
    __shared__ int lofs[NBUCK];
    const int t = threadIdx.x;
    lbase[t] = bbase[t] + bcnt[t * PB_BLOCKS + blockIdx.x];
    lofs[t] = 0;
    __syncthreads();
    const int beg = blockIdx.x * CHUNK;
    const int end = min(beg + CHUNK, NNZ);
    for (int i = beg + t; i < end; i += 256) {
        const int r = rows[i];
        const int b = r >> 11;
        const int p = lbase[b] + atomicAdd(&lofs[b], 1);
        eb[p]    = make_int2(cols[i], __float_as_int(vals[i]));
        ebrow[p] = (unsigned short)(r & (ROWS_PER_BUCK - 1));
    }
}

__global__ void bucket_finalize(const int* __restrict__ bbase,
                                const int2* __restrict__ eb,
                                const unsigned short* __restrict__ ebrow,
                                int* __restrict__ row_ptr, int2* __restrict__ sc) {
    __shared__ int  lcnt[ROWS_PER_BUCK];
    __shared__ int  tmp[256];
    __shared__ int2 lout[BCAP];
    const int b    = blockIdx.x;
    const int t    = threadIdx.x;
    const int base = bbase[b];
    const int cnt  = bbase[b + 1] - base;
    for (int r = t; r < ROWS_PER_BUCK; r += 256) lcnt[r] = 0;
    __syncthreads();
    for (int i = t; i < cnt; i += 256)
        atomicAdd(&lcnt[ebrow[base + i]], 1);
    __syncthreads();
    int loc[8];
    int run = 0;
    #pragma unroll
    for (int k = 0; k < 8; ++k) { const int v = lcnt[t * 8 + k]; loc[k] = run; run += v; }
    tmp[t] = run;
    __syncthreads();
    for (int off = 1; off < 256; off <<= 1) {
        int x = (t >= off) ? tmp[t - off] : 0;
        __syncthreads();
        tmp[t] += x;
        __syncthreads();
    }
    const int excl = tmp[t] - run;
    #pragma unroll
    for (int k = 0; k < 8; ++k) lcnt[t * 8 + k] = loc[k] + excl;
    __syncthreads();
    for (int r = t; r < ROWS_PER_BUCK; r += 256)
        row_ptr[b * ROWS_PER_BUCK + r] = base + lcnt[r];
    if (b == NBUCK - 1 && t == 0) row_ptr[N_NODES] = NNZ;
    __syncthreads();
    if (cnt <= BCAP) {
        for (int i = t; i < cnt; i += 256) {
            const int p = atomicAdd(&lcnt[ebrow[base + i]], 1);
            lout[p] = eb[base + i];
        }
        __syncthreads();
        for (int i = t; i < cnt; i += 256)
            sc[base + i] = lout[i];
    } else {
        for (int i = t; i < cnt; i += 256) {
            const int p = atomicAdd(&lcnt[ebrow[base + i]], 1);
            sc[base + p] = eb[base + i];
        }
    }
}

// ---------------- SpMM layers (8 lanes/row, 8 rows/wave) ----------------
// layer 1: f32 gathers from ue/ie; writes e1b AND s1b = bf16(ego + e1)
__global__ void spmm_first(const int* __restrict__ ptr, const int2* __restrict__ sc,
                           const float4* __restrict__ ue4, const float4* __restrict__ ie4,
                           uint4* __restrict__ e1b, uint4* __restrict__ s1b) {
    const int row = blockIdx.x * 32 + (threadIdx.x >> 3);
    const int d8  = threadIdx.x & 7;
    const int beg = ptr[row];
    const int end = ptr[row + 1];
    // hoisted own-row ego loads (coalesced, in flight during the edge loop)
    const float4* pg = (row < NUM_USER) ? ue4 + (size_t)row * 16
                                        : ie4 + (size_t)(row - NUM_USER) * 16;
    const float4 gl = pg[2 * d8];
    const float4 gh = pg[2 * d8 + 1];
    float4 a0 = {0.f,0.f,0.f,0.f}, b0 = {0.f,0.f,0.f,0.f};
    float4 a1 = {0.f,0.f,0.f,0.f}, b1 = {0.f,0.f,0.f,0.f};
    int e = beg;
    for (; e + 2 <= end; e += 2) {
        const int2 A = sc[e];
        const int2 B = sc[e + 1];
        const float4* pa = (A.x < NUM_USER) ? ue4 + (size_t)A.x * 16
                                            : ie4 + (size_t)(A.x - NUM_USER) * 16;
        const float4* pb = (B.x < NUM_USER) ? ue4 + (size_t)B.x * 16
                                            : ie4 + (size_t)(B.x - NUM_USER) * 16;
        const float4 al = pa[2 * d8], ah = pa[2 * d8 + 1];
        const float4 bl = pb[2 * d8], bh = pb[2 * d8 + 1];
        const float va = __int_as_float(A.y);
        const float vb = __int_as_float(B.y);
        fma4(a0, va, al); fma4(b0, va, ah);
        fma4(a1, vb, bl); fma4(b1, vb, bh);
    }
    if (e < end) {
        const int2 A = sc[e];
        const float4* pa = (A.x < NUM_USER) ? ue4 + (size_t)A.x * 16
                                            : ie4 + (size_t)(A.x - NUM_USER) * 16;
        const float va = __int_as_float(A.y);
        fma4(a0, va, pa[2 * d8]); fma4(b0, va, pa[2 * d8 + 1]);
    }
    const float4 sl = add4(a0, a1), sh = add4(b0, b1);
    const int o8 = row * 8 + d8;
    e1b[o8] = bfpack8(sl, sh);
    s1b[o8] = bfpack8(add4(sl, gl), add4(sh, gh));
}

// layer 2: bf16 gathers, 2-deep pipelined edge loop
__global__ void spmm_b2b(const int* __restrict__ ptr, const int2* __restrict__ sc,
                         const uint4* __restrict__ xb, uint4* __restrict__ yb) {
    const int row = blockIdx.x * 32 + (threadIdx.x >> 3);
    const int d8  = threadIdx.x & 7;
    const int beg = ptr[row];
    const int end = ptr[row + 1];
    float4 a0 = {0.f,0.f,0.f,0.f}, b0 = {0.f,0.f,0.f,0.f};
    float4 a1 = {0.f,0.f,0.f,0.f}, b1 = {0.f,0.f,0.f,0.f};
    bool h0 = beg < end, h1 = beg + 1 < end;
    int2 A0 = {0, 0}, A1 = {0, 0};
    uint4 X0 = {0,0,0,0}, X1 = {0,0,0,0};
    if (h0) { A0 = sc[beg];     X0 = xb[A0.x * 8 + d8]; }
    if (h1) { A1 = sc[beg + 1]; X1 = xb[A1.x * 8 + d8]; }
    int e = beg + 2;
    while (h0) {
        const bool nh0 = e < end, nh1 = e + 1 < end;
        int2 nA0 = {0, 0}, nA1 = {0, 0};
        uint4 nX0 = {0,0,0,0}, nX1 = {0,0,0,0};
        if (nh0) { nA0 = sc[e];     nX0 = xb[nA0.x * 8 + d8]; }
        if (nh1) { nA1 = sc[e + 1]; nX1 = xb[nA1.x * 8 + d8]; }
        {
            float4 l, h;
            bfunpack8(X0, l, h);
            fma4(a0, __int_as_float(A0.y), l); fma4(b0, __int_as_float(A0.y), h);
        }
        if (h1) {
            float4 l, h;
            bfunpack8(X1, l, h);
            fma4(a1, __int_as_float(A1.y), l); fma4(b1, __int_as_float(A1.y), h);
        }
        h0 = nh0; h1 = nh1; A0 = nA0; A1 = nA1; X0 = nX0; X1 = nX1;
        e += 2;
    }
    yb[row * 8 + d8] = bfpack8(add4(a0, a1), add4(b0, b1));
}

// layer 3: e3 in regs, 2-deep pipeline; out = (s1 + e2 + e3)/4, f32
__global__ void spmm_last(const int* __restrict__ ptr, const int2* __restrict__ sc,
                          const uint4* __restrict__ s1b, const uint4* __restrict__ e2b,
                          float4* __restrict__ out4) {
    const int row = blockIdx.x * 32 + (threadIdx.x >> 3);
    const int d8  = threadIdx.x & 7;
    const int beg = ptr[row];
    const int end = ptr[row + 1];
    // hoisted epilogue loads
    const int o8 = row * 8 + d8;
    const uint4 u1 = s1b[o8];
    const uint4 u2 = e2b[o8];
    float4 a0 = {0.f,0.f,0.f,0.f}, b0 = {0.f,0.f,0.f,0.f};
    float4 a1 = {0.f,0.f,0.f,0.f}, b1 = {0.f,0.f,0.f,0.f};
    bool h0 = beg < end, h1 = beg + 1 < end;
    int2 A0 = {0, 0}, A1 = {0, 0};
    uint4 X0 = {0,0,0,0}, X1 = {0,0,0,0};
    if (h0) { A0 = sc[beg];     X0 = e2b[A0.x * 8 + d8]; }
    if (h1) { A1 = sc[beg + 1]; X1 = e2b[A1.x * 8 + d8]; }
    int e = beg + 2;
    while (h0) {
        const bool nh0 = e < end, nh1 = e + 1 < end;
        int2 nA0 = {0, 0}, nA1 = {0, 0};
        uint4 nX0 = {0,0,0,0}, nX1 = {0,0,0,0};
        if (nh0) { nA0 = sc[e];     nX0 = e2b[nA0.x * 8 + d8]; }
        if (nh1) { nA1 = sc[e + 1]; nX1 = e2b[nA1.x * 8 + d8]; }
        {
            float4 l, h;
            bfunpack8(X0, l, h);
            fma4(a0, __int_as_float(A0.y), l); fma4(b0, __int_as_float(A0.y), h);
        }
        if (h1) {
            float4 l, h;
            bfunpack8(X1, l, h);
            fma4(a1, __int_as_float(A1.y), l); fma4(b1, __int_as_float(A1.y), h);
        }
        h0 = nh0; h1 = nh1; A0 = nA0; A1 = nA1; X0 = nX0; X1 = nX1;
        e += 2;
    }
    a0 = add4(a0, a1); b0 = add4(b0, b1);
    float4 l1, h1f, l2, h2;
    bfunpack8(u1, l1, h1f);
    bfunpack8(u2, l2, h2);
    float4 r0, r1;
    r0.x = (l1.x + l2.x + a0.x) * 0.25f;
    r0.y = (l1.y + l2.y + a0.y) * 0.25f;
    r0.z = (l1.z + l2.z + a0.z) * 0.25f;
    r0.w = (l1.w + l2.w + a0.w) * 0.25f;
    r1.x = (h1f.x + h2.x + b0.x) * 0.25f;
    r1.y = (h1f.y + h2.y + b0.y) * 0.25f;
    r1.z = (h1f.z + h2.z + b0.z) * 0.25f;
    r1.w = (h1f.w + h2.w + b0.w) * 0.25f;
    out4[row * 16 + 2 * d8]     = r0;
    out4[row * 16 + 2 * d8 + 1] = r1;
}

// ---------------- fallback (round-1 proven path) ----------------
__global__ void lgcn_init(const float4* __restrict__ ue, const float4* __restrict__ ie,
                          float4* __restrict__ cur, float4* __restrict__ acc) {
    const long total  = (long)N_NODES * (DIM / 4);
    const long utotal = (long)NUM_USER * (DIM / 4);
    long i = (long)blockIdx.x * blockDim.x + threadIdx.x;
    const long stride = (long)gridDim.x * blockDim.x;
    for (; i < total; i += stride) {
        float4 v = (i < utotal) ? ue[i] : ie[i - utotal];
        cur[i] = v;
        acc[i] = v;
    }
}

__global__ void lgcn_spmm_atomic(const int* __restrict__ rows, const int* __restrict__ cols,
                                 const float* __restrict__ vals, const float* __restrict__ x,
                                 float* __restrict__ y) {
    const long total  = (long)NNZ * DIM;
    long t = (long)blockIdx.x * blockDim.x + threadIdx.x;
    const long stride = (long)gridDim.x * blockDim.x;
    for (; t < total; t += stride) {
        const int e = (int)(t >> 6);
        const int d = (int)(t & 63);
        atomicAdd(&y[((long)rows[e] << 6) + d], vals[e] * x[((long)cols[e] << 6) + d]);
    }
}

__global__ void lgcn_add(float4* __restrict__ acc, const float4* __restrict__ nxt, float scale) {
    const long total  = (long)N_NODES * (DIM / 4);
    long i = (long)blockIdx.x * blockDim.x + threadIdx.x;
    const long stride = (long)gridDim.x * blockDim.x;
    for (; i < total; i += stride) {
        float4 a = acc[i];
        const float4 b = nxt[i];
        a.x = (a.x + b.x) * scale;
        a.y = (a.y + b.y) * scale;
        a.z = (a.z + b.z) * scale;
        a.w = (a.w + b.w) * scale;
        acc[i] = a;
    }
}

extern "C" void kernel_launch(void* const* d_in, const int* in_sizes, int n_in,
                              void* d_out, int out_size, void* d_ws, size_t ws_size,
                              hipStream_t stream) {
    const float* ue   = (const float*)d_in[0];
    const float* ie   = (const float*)d_in[1];
    const int*   rows = (const int*)d_in[2];
    const int*   cols = (const int*)d_in[3];
    const float* vals = (const float*)d_in[4];
    float* out = (float*)d_out;

    const size_t embBytes  = (size_t)N_NODES * DIM * sizeof(float);  // 134,217,728
    const size_t embBytesH = embBytes / 2;                           // 67,108,864
    char* ws = (char*)d_ws;
    uint4* e1b = (uint4*)ws;                                         // 67 MB
    uint4* e2b = (uint4*)(ws + embBytesH);                           // 67 MB
    uint4* s1b = (uint4*)(ws + 2 * embBytesH);                       // 67 MB (ego+e1)
    char* p = ws + 3 * embBytesH;
    int2* sc = (int2*)p;                 p += (size_t)NNZ * 8;       // 10 MB
    int2* eb = (int2*)p;                 p += (size_t)NNZ * 8;       // 10 MB
    unsigned short* ebrow = (unsigned short*)p; p += (size_t)NNZ * 2;// 2.5 MB
    int* row_ptr = (int*)p;              p += (size_t)(N_NODES + 1) * 4;
    int* bcnt    = (int*)p;              p += (size_t)NBUCK * PB_BLOCKS * 4;  // 256 KB
    int* tot     = (int*)p;              p += (size_t)NBUCK * 4;
    int* bbase   = (int*)p;              p += (size_t)(NBUCK + 1) * 4;
    const size_t need = (size_t)(p - ws);

    if (ws_size >= need) {
        // ---- histogram-free bucketed CSR build + edge sort ----
        bucket_count   <<<PB_BLOCKS, 256, 0, stream>>>(rows, bcnt);
        scan_bcnt      <<<NBUCK,     256, 0, stream>>>(bcnt, tot);
        scan_btot      <<<1,         256, 0, stream>>>(tot, bbase);
        bucket_scatter <<<PB_BLOCKS, 256, 0, stream>>>(rows, cols, vals, bcnt, bbase,
                                                       eb, ebrow);
        bucket_finalize<<<NBUCK,     256, 0, stream>>>(bbase, eb, ebrow, row_ptr, sc);

        // ---- 3 layers; mean fused into layer 3 ----
        spmm_first<<<N_NODES / 32, 256, 0, stream>>>(row_ptr, sc,
                                                     (const float4*)ue, (const float4*)ie,
                                                     e1b, s1b);
        spmm_b2b  <<<N_NODES / 32, 256, 0, stream>>>(row_ptr, sc, e1b, e2b);
        spmm_last <<<N_NODES / 32, 256, 0, stream>>>(row_ptr, sc, s1b, e2b, (float4*)out);
    } else {
        // ---- fallback: round-1 proven path (needs 2*embBytes) ----
        float* buf0 = (float*)ws;
        float* buf1 = (float*)(ws + embBytes);
        lgcn_init<<<4096, 256, 0, stream>>>((const float4*)ue, (const float4*)ie,
                                            (float4*)buf0, (float4*)out);
        float* cur = buf0;
        float* nxt = buf1;
        for (int l = 0; l < 3; ++l) {
            hipMemsetAsync(nxt, 0, embBytes, stream);
            lgcn_spmm_atomic<<<2048, 256, 0, stream>>>(rows, cols, vals, cur, nxt);
            const float scale = (l == 2) ? 0.25f : 1.0f;
            lgcn_add<<<4096, 256, 0, stream>>>((float4*)out, (const float4*)nxt, scale);
            float* t = cur; cur = nxt; nxt = t;
        }
    }
}

// Round 12
// 240.634 us; speedup vs baseline: 1.1731x; 1.1731x over previous
//
#include <hip/hip_runtime.h>

// LightGCN propagation on MI355X — bf16 states, bucketed CSR, 8-lane SpMM.
// R11 lesson: the ego-fold was a traffic shuffle (moved 134MB from last to
// first, +65MB write) — net regression. R12 = revert to the proven R10
// structure + two narrow deltas: (1) int4-vectorized edge reads in
// bucket_count/bucket_scatter; (2) nontemporal store for the final out write
// (never re-read; keeps e2b gather target L3-resident).

constexpr int NUM_USER = 262144;
constexpr int NUM_ITEM = 262144;
constexpr int DIM      = 64;
constexpr int N_NODES  = NUM_USER + NUM_ITEM;   // 524288
constexpr int NNZ      = 1250000;

constexpr int NBUCK = 256;                      // bucket = row >> 11
constexpr int ROWS_PER_BUCK = N_NODES / NBUCK;  // 2048
constexpr int PB_BLOCKS = 512;
constexpr int CHUNK = 2444;                     // mult of 4; 512*2444 >= NNZ
constexpr int BCAP = 6144;                      // bucket mean 4883, sd ~70

typedef float  __f4 __attribute__((ext_vector_type(4)));

// ---------------- bf16 pack/unpack (RNE) ----------------
__device__ __forceinline__ unsigned bfpack2(float a, float b) {
    unsigned ua = __float_as_uint(a); ua += 0x7fffu + ((ua >> 16) & 1u);
    unsigned ub = __float_as_uint(b); ub += 0x7fffu + ((ub >> 16) & 1u);
    return (ua >> 16) | (ub & 0xffff0000u);
}
__device__ __forceinline__ uint4 bfpack8(float4 a, float4 b) {
    return make_uint4(bfpack2(a.x, a.y), bfpack2(a.z, a.w),
                      bfpack2(b.x, b.y), bfpack2(b.z, b.w));
}
__device__ __forceinline__ void bfunpack8(uint4 u, float4& l, float4& h) {
    l.x = __uint_as_float(u.x << 16);
    l.y = __uint_as_float(u.x & 0xffff0000u);
    l.z = __uint_as_float(u.y << 16);
    l.w = __uint_as_float(u.y & 0xffff0000u);
    h.x = __uint_as_float(u.z << 16);
    h.y = __uint_as_float(u.z & 0xffff0000u);
    h.z = __uint_as_float(u.w << 16);
    h.w = __uint_as_float(u.w & 0xffff0000u);
}
__device__ __forceinline__ void fma4(float4& s, float v, const float4 x) {
    s.x = fmaf(v, x.x, s.x);
    s.y = fmaf(v, x.y, s.y);
    s.z = fmaf(v, x.z, s.z);
    s.w = fmaf(v, x.w, s.w);
}
__device__ __forceinline__ float4 add4(float4 a, float4 b) {
    return make_float4(a.x + b.x, a.y + b.y, a.z + b.z, a.w + b.w);
}

// ---------------- bucket pipeline ----------------
// k1: per-block bucket histogram, int4-vectorized edge reads
__global__ void bucket_count(const int* __restrict__ rows, int* __restrict__ bcnt) {
    __shared__ int lcnt[NBUCK];
    const int t = threadIdx.x;
    lcnt[t] = 0;
    __syncthreads();
    const int beg = blockIdx.x * CHUNK;
    const int end = min(beg + CHUNK, NNZ);
    const int n    = max(end - beg, 0);
    const int nvec = n >> 2;
    const int4* rows4 = (const int4*)(rows + beg);
    for (int i = t; i < nvec; i += 256) {
        const int4 r = rows4[i];
        atomicAdd(&lcnt[r.x >> 11], 1);
        atomicAdd(&lcnt[r.y >> 11], 1);
        atomicAdd(&lcnt[r.z >> 11], 1);
        atomicAdd(&lcnt[r.w >> 11], 1);
    }
    if (t < (n & 3)) atomicAdd(&lcnt[rows[beg + (nvec << 2) + t] >> 11], 1);
    __syncthreads();
    bcnt[t * PB_BLOCKS + blockIdx.x] = lcnt[t];
}

// k2a: per bucket, exclusive scan over the 512 block counts (in place)
__global__ void scan_bcnt(int* __restrict__ bcnt, int* __restrict__ tot) {
    __shared__ int tmp[256];
    const int b = blockIdx.x, t = threadIdx.x;
    const int a0 = bcnt[b * PB_BLOCKS + 2 * t];
    const int a1 = bcnt[b * PB_BLOCKS + 2 * t + 1];
    const int run = a0 + a1;
    tmp[t] = run;
    __syncthreads();
    for (int off = 1; off < 256; off <<= 1) {
        int x = (t >= off) ? tmp[t - off] : 0;
        __syncthreads();
        tmp[t] += x;
        __syncthreads();
    }
    const int excl = tmp[t] - run;
    bcnt[b * PB_BLOCKS + 2 * t]     = excl;
    bcnt[b * PB_BLOCKS + 2 * t + 1] = excl + a0;
    if (t == 255) tot[b] = tmp[255];
}

// k2b: exclusive scan of the 256 bucket totals -> bbase[257]
__global__ void scan_btot(const int* __restrict__ tot, int* __restrict__ bbase) {
    __shared__ int tmp[256];
    const int t = threadIdx.x;
    const int v = tot[t];
    tmp[t] = v;
    __syncthreads();
    for (int off = 1; off < 256; off <<= 1) {
        int x = (t >= off) ? tmp[t - off] : 0;
        __syncthreads();
        tmp[t] += x;
        __syncthreads();
    }
    bbase[t] = tmp[t] - v;
    if (t == 0) bbase[NBUCK] = NNZ;
}

// k3: grouped scatter, int4/float4-vectorized edge reads
__global__ void bucket_scatter(const int* __restrict__ rows, const int* __restrict__ cols,
                               const float* __restrict__ vals,
                               const int* __restrict__ bcnt, const int* __restrict__ bbase,
                               int2* __restrict__ eb, unsigned short* __restrict__ ebrow) {
    __shared__ int lbase[NBUCK];
    __shared__ int lofs[NBUCK];
    const int t = threadIdx.x;
    lbase[t] = bbase[t] + bcnt[t * PB_BLOCKS + blockIdx.x];
    lofs[t] = 0;
    __syncthreads();
    const int beg = blockIdx.x * CHUNK;
    const int end = min(beg + CHUNK, NNZ);
    const int n    = max(end - beg, 0);
    const int nvec = n >> 2;
    const int4*   rows4 = (const int4*)(rows + beg);
    const int4*   cols4 = (const int4*)(cols + beg);
    const float4* vals4 = (const float4*)(vals + beg);
    for (int i = t; i < nvec; i += 256) {
        const int4   r = rows4[i];
        const int4   c = cols4[i];
        const float4 v = vals4[i];
        int b, p;
        b = r.x >> 11; p = lbase[b] + atomicAdd(&lofs[b], 1);
        eb[p] = make_int2(c.x, __float_as_int(v.x));
        ebrow[p] = (unsigned short)(r.x & (ROWS_PER_BUCK - 1));
        b = r.y >> 11; p = lbase[b] + atomicAdd(&lofs[b], 1);
        eb[p] = make_int2(c.y, __float_as_int(v.y));
        ebrow[p] = (unsigned short)(r.y & (ROWS_PER_BUCK - 1));
        b = r.z >> 11; p = lbase[b] + atomicAdd(&lofs[b], 1);
        eb[p] = make_int2(c.z, __float_as_int(v.z));
        ebrow[p] = (unsigned short)(r.z & (ROWS_PER_BUCK - 1));
        b = r.w >> 11; p = lbase[b] + atomicAdd(&lofs[b], 1);
        eb[p] = make_int2(c.w, __float_as_int(v.w));
        ebrow[p] = (unsigned short)(r.w & (ROWS_PER_BUCK - 1));
    }
    if (t < (n & 3)) {
        const int i = beg + (nvec << 2) + t;
        const int r = rows[i];
        const int b = r >> 11;
        const int p = lbase[b] + atomicAdd(&lofs[b], 1);
        eb[p] = make_int2(cols[i], __float_as_int(vals[i]));
        ebrow[p] = (unsigned short)(r & (ROWS_PER_BUCK - 1));
    }
}

// k4: per bucket — row histogram, 2048-scan, row_ptr write, LDS permute -> sc
__global__ void bucket_finalize(const int* __restrict__ bbase,
                                const int2* __restrict__ eb,
                                const unsigned short* __restrict__ ebrow,
                                int* __restrict__ row_ptr, int2* __restrict__ sc) {
    __shared__ int  lcnt[ROWS_PER_BUCK];
    __shared__ int  tmp[256];
    __shared__ int2 lout[BCAP];
    const int b    = blockIdx.x;
    const int t    = threadIdx.x;
    const int base = bbase[b];
    const int cnt  = bbase[b + 1] - base;
    for (int r = t; r < ROWS_PER_BUCK; r += 256) lcnt[r] = 0;
    __syncthreads();
    for (int i = t; i < cnt; i += 256)
        atomicAdd(&lcnt[ebrow[base + i]], 1);
    __syncthreads();
    int loc[8];
    int run = 0;
    #pragma unroll
    for (int k = 0; k < 8; ++k) { const int v = lcnt[t * 8 + k]; loc[k] = run; run += v; }
    tmp[t] = run;
    __syncthreads();
    for (int off = 1; off < 256; off <<= 1) {
        int x = (t >= off) ? tmp[t - off] : 0;
        __syncthreads();
        tmp[t] += x;
        __syncthreads();
    }
    const int excl = tmp[t] - run;
    #pragma unroll
    for (int k = 0; k < 8; ++k) lcnt[t * 8 + k] = loc[k] + excl;
    __syncthreads();
    for (int r = t; r < ROWS_PER_BUCK; r += 256)
        row_ptr[b * ROWS_PER_BUCK + r] = base + lcnt[r];
    if (b == NBUCK - 1 && t == 0) row_ptr[N_NODES] = NNZ;
    __syncthreads();
    if (cnt <= BCAP) {
        for (int i = t; i < cnt; i += 256) {
            const int p = atomicAdd(&lcnt[ebrow[base + i]], 1);
            lout[p] = eb[base + i];
        }
        __syncthreads();
        for (int i = t; i < cnt; i += 256)
            sc[base + i] = lout[i];
    } else {
        for (int i = t; i < cnt; i += 256) {
            const int p = atomicAdd(&lcnt[ebrow[base + i]], 1);
            sc[base + p] = eb[base + i];
        }
    }
}

// ---------------- SpMM layers (all 8 lanes/row, 8 rows/wave) ----------------
// layer 1: f32 gathers from ue/ie (2x float4 per lane), writes bf16 e1
__global__ void spmm_first(const int* __restrict__ ptr, const int2* __restrict__ sc,
                           const float4* __restrict__ ue4, const float4* __restrict__ ie4,
                           uint4* __restrict__ e1b) {
    const int row = blockIdx.x * 32 + (threadIdx.x >> 3);
    const int d8  = threadIdx.x & 7;
    const int beg = ptr[row];
    const int end = ptr[row + 1];
    float4 a0 = {0.f,0.f,0.f,0.f}, b0 = {0.f,0.f,0.f,0.f};
    float4 a1 = {0.f,0.f,0.f,0.f}, b1 = {0.f,0.f,0.f,0.f};
    int e = beg;
    for (; e + 2 <= end; e += 2) {
        const int2 A = sc[e];
        const int2 B = sc[e + 1];
        const float4* pa = (A.x < NUM_USER) ? ue4 + (size_t)A.x * 16
                                            : ie4 + (size_t)(A.x - NUM_USER) * 16;
        const float4* pb = (B.x < NUM_USER) ? ue4 + (size_t)B.x * 16
                                            : ie4 + (size_t)(B.x - NUM_USER) * 16;
        const float4 al = pa[2 * d8], ah = pa[2 * d8 + 1];
        const float4 bl = pb[2 * d8], bh = pb[2 * d8 + 1];
        const float va = __int_as_float(A.y);
        const float vb = __int_as_float(B.y);
        fma4(a0, va, al); fma4(b0, va, ah);
        fma4(a1, vb, bl); fma4(b1, vb, bh);
    }
    if (e < end) {
        const int2 A = sc[e];
        const float4* pa = (A.x < NUM_USER) ? ue4 + (size_t)A.x * 16
                                            : ie4 + (size_t)(A.x - NUM_USER) * 16;
        const float va = __int_as_float(A.y);
        fma4(a0, va, pa[2 * d8]); fma4(b0, va, pa[2 * d8 + 1]);
    }
    e1b[row * 8 + d8] = bfpack8(add4(a0, a1), add4(b0, b1));
}

// layer 2: bf16 gathers (uint4 per lane)
__global__ void spmm_b2b(const int* __restrict__ ptr, const int2* __restrict__ sc,
                         const uint4* __restrict__ xb, uint4* __restrict__ yb) {
    const int row = blockIdx.x * 32 + (threadIdx.x >> 3);
    const int d8  = threadIdx.x & 7;
    const int beg = ptr[row];
    const int end = ptr[row + 1];
    float4 a0 = {0.f,0.f,0.f,0.f}, b0 = {0.f,0.f,0.f,0.f};
    float4 a1 = {0.f,0.f,0.f,0.f}, b1 = {0.f,0.f,0.f,0.f};
    int e = beg;
    for (; e + 2 <= end; e += 2) {
        const int2 A = sc[e];
        const int2 B = sc[e + 1];
        const uint4 xa = xb[A.x * 8 + d8];
        const uint4 xc = xb[B.x * 8 + d8];
        float4 l, h;
        bfunpack8(xa, l, h);
        fma4(a0, __int_as_float(A.y), l); fma4(b0, __int_as_float(A.y), h);
        bfunpack8(xc, l, h);
        fma4(a1, __int_as_float(B.y), l); fma4(b1, __int_as_float(B.y), h);
    }
    if (e < end) {
        const int2 A = sc[e];
        float4 l, h;
        bfunpack8(xb[A.x * 8 + d8], l, h);
        fma4(a0, __int_as_float(A.y), l); fma4(b0, __int_as_float(A.y), h);
    }
    yb[row * 8 + d8] = bfpack8(add4(a0, a1), add4(b0, b1));
}

// layer 3: e3 in regs; out = (ego_f32 + e1 + e2 + e3)/4; NT store for out.
__global__ void spmm_last(const int* __restrict__ ptr, const int2* __restrict__ sc,
                          const float4* __restrict__ ue4, const float4* __restrict__ ie4,
                          const uint4* __restrict__ e1b, const uint4* __restrict__ e2b,
                          float4* __restrict__ out4) {
    const int row = blockIdx.x * 32 + (threadIdx.x >> 3);
    const int d8  = threadIdx.x & 7;
    const int beg = ptr[row];
    const int end = ptr[row + 1];
    // hoisted epilogue loads (coalesced; in flight during the edge loop)
    const int o8 = row * 8 + d8;
    const float4* pg = (row < NUM_USER) ? ue4 + (size_t)row * 16
                                        : ie4 + (size_t)(row - NUM_USER) * 16;
    const float4 gl = pg[2 * d8];
    const float4 gh = pg[2 * d8 + 1];
    const uint4 u1 = e1b[o8];
    const uint4 u2 = e2b[o8];
    float4 a0 = {0.f,0.f,0.f,0.f}, b0 = {0.f,0.f,0.f,0.f};
    float4 a1 = {0.f,0.f,0.f,0.f}, b1 = {0.f,0.f,0.f,0.f};
    int e = beg;
    for (; e + 2 <= end; e += 2) {
        const int2 A = sc[e];
        const int2 B = sc[e + 1];
        const uint4 xa = e2b[A.x * 8 + d8];
        const uint4 xc = e2b[B.x * 8 + d8];
        float4 l, h;
        bfunpack8(xa, l, h);
        fma4(a0, __int_as_float(A.y), l); fma4(b0, __int_as_float(A.y), h);
        bfunpack8(xc, l, h);
        fma4(a1, __int_as_float(B.y), l); fma4(b1, __int_as_float(B.y), h);
    }
    if (e < end) {
        const int2 A = sc[e];
        float4 l, h;
        bfunpack8(e2b[A.x * 8 + d8], l, h);
        fma4(a0, __int_as_float(A.y), l); fma4(b0, __int_as_float(A.y), h);
    }
    a0 = add4(a0, a1); b0 = add4(b0, b1);
    float4 l1, h1, l2, h2;
    bfunpack8(u1, l1, h1);
    bfunpack8(u2, l2, h2);
    float4 r0, r1;
    r0.x = (gl.x + l1.x + l2.x + a0.x) * 0.25f;
    r0.y = (gl.y + l1.y + l2.y + a0.y) * 0.25f;
    r0.z = (gl.z + l1.z + l2.z + a0.z) * 0.25f;
    r0.w = (gl.w + l1.w + l2.w + a0.w) * 0.25f;
    r1.x = (gh.x + h1.x + h2.x + b0.x) * 0.25f;
    r1.y = (gh.y + h1.y + h2.y + b0.y) * 0.25f;
    r1.z = (gh.z + h1.z + h2.z + b0.z) * 0.25f;
    r1.w = (gh.w + h1.w + h2.w + b0.w) * 0.25f;
    // nontemporal stores: out is never re-read; don't displace e2b from L2/L3
    __builtin_nontemporal_store(*(const __f4*)&r0, (__f4*)&out4[row * 16 + 2 * d8]);
    __builtin_nontemporal_store(*(const __f4*)&r1, (__f4*)&out4[row * 16 + 2 * d8 + 1]);
}

// ---------------- fallback (round-1 proven path) ----------------
__global__ void lgcn_init(const float4* __restrict__ ue, const float4* __restrict__ ie,
                          float4* __restrict__ cur, float4* __restrict__ acc) {
    const long total  = (long)N_NODES * (DIM / 4);
    const long utotal = (long)NUM_USER * (DIM / 4);
    long i = (long)blockIdx.x * blockDim.x + threadIdx.x;
    const long stride = (long)gridDim.x * blockDim.x;
    for (; i < total; i += stride) {
        float4 v = (i < utotal) ? ue[i] : ie[i - utotal];
        cur[i] = v;
        acc[i] = v;
    }
}

__global__ void lgcn_spmm_atomic(const int* __restrict__ rows, const int* __restrict__ cols,
                                 const float* __restrict__ vals, const float* __restrict__ x,
                                 float* __restrict__ y) {
    const long total  = (long)NNZ * DIM;
    long t = (long)blockIdx.x * blockDim.x + threadIdx.x;
    const long stride = (long)gridDim.x * blockDim.x;
    for (; t < total; t += stride) {
        const int e = (int)(t >> 6);
        const int d = (int)(t & 63);
        atomicAdd(&y[((long)rows[e] << 6) + d], vals[e] * x[((long)cols[e] << 6) + d]);
    }
}

__global__ void lgcn_add(float4* __restrict__ acc, const float4* __restrict__ nxt, float scale) {
    const long total  = (long)N_NODES * (DIM / 4);
    long i = (long)blockIdx.x * blockDim.x + threadIdx.x;
    const long stride = (long)gridDim.x * blockDim.x;
    for (; i < total; i += stride) {
        float4 a = acc[i];
        const float4 b = nxt[i];
        a.x = (a.x + b.x) * scale;
        a.y = (a.y + b.y) * scale;
        a.z = (a.z + b.z) * scale;
        a.w = (a.w + b.w) * scale;
        acc[i] = a;
    }
}

extern "C" void kernel_launch(void* const* d_in, const int* in_sizes, int n_in,
                              void* d_out, int out_size, void* d_ws, size_t ws_size,
                              hipStream_t stream) {
    const float* ue   = (const float*)d_in[0];
    const float* ie   = (const float*)d_in[1];
    const int*   rows = (const int*)d_in[2];
    const int*   cols = (const int*)d_in[3];
    const float* vals = (const float*)d_in[4];
    float* out = (float*)d_out;

    const size_t embBytes  = (size_t)N_NODES * DIM * sizeof(float);  // 134,217,728
    const size_t embBytesH = embBytes / 2;                           // 67,108,864
    char* ws = (char*)d_ws;
    uint4* e1b = (uint4*)ws;                                         // 67 MB
    uint4* e2b = (uint4*)(ws + embBytesH);                           // 67 MB
    char* p = ws + 2 * embBytesH;
    int2* sc = (int2*)p;                 p += (size_t)NNZ * 8;       // 10 MB
    int2* eb = (int2*)p;                 p += (size_t)NNZ * 8;       // 10 MB
    unsigned short* ebrow = (unsigned short*)p; p += (size_t)NNZ * 2;// 2.5 MB
    int* row_ptr = (int*)p;              p += (size_t)(N_NODES + 1) * 4;
    int* bcnt    = (int*)p;              p += (size_t)NBUCK * PB_BLOCKS * 4;  // 512 KB
    int* tot     = (int*)p;              p += (size_t)NBUCK * 4;
    int* bbase   = (int*)p;              p += (size_t)(NBUCK + 1) * 4;
    const size_t need = (size_t)(p - ws);

    if (ws_size >= need) {
        // ---- histogram-free bucketed CSR build + edge sort ----
        bucket_count   <<<PB_BLOCKS, 256, 0, stream>>>(rows, bcnt);
        scan_bcnt      <<<NBUCK,     256, 0, stream>>>(bcnt, tot);
        scan_btot      <<<1,         256, 0, stream>>>(tot, bbase);
        bucket_scatter <<<PB_BLOCKS, 256, 0, stream>>>(rows, cols, vals, bcnt, bbase,
                                                       eb, ebrow);
        bucket_finalize<<<NBUCK,     256, 0, stream>>>(bbase, eb, ebrow, row_ptr, sc);

        // ---- 3 layers; mean fused into layer 3 ----
        spmm_first<<<N_NODES / 32, 256, 0, stream>>>(row_ptr, sc,
                                                     (const float4*)ue, (const float4*)ie,
                                                     e1b);
        spmm_b2b  <<<N_NODES / 32, 256, 0, stream>>>(row_ptr, sc, e1b, e2b);
        spmm_last <<<N_NODES / 32, 256, 0, stream>>>(row_ptr, sc,
                                                     (const float4*)ue, (const float4*)ie,
                                                     e1b, e2b, (float4*)out);
    } else {
        // ---- fallback: round-1 proven path (needs 2*embBytes) ----
        float* buf0 = (float*)ws;
        float* buf1 = (float*)(ws + embBytes);
        lgcn_init<<<4096, 256, 0, stream>>>((const float4*)ue, (const float4*)ie,
                                            (float4*)buf0, (float4*)out);
        float* cur = buf0;
        float* nxt = buf1;
        for (int l = 0; l < 3; ++l) {
            hipMemsetAsync(nxt, 0, embBytes, stream);
            lgcn_spmm_atomic<<<2048, 256, 0, stream>>>(rows, cols, vals, cur, nxt);
            const float scale = (l == 2) ? 0.25f : 1.0f;
            lgcn_add<<<4096, 256, 0, stream>>>((float4*)out, (const float4*)nxt, scale);
            float* t = cur; cur = nxt; nxt = t;
        }
    }
}